// Round 4
// baseline (396.539 us; speedup 1.0000x reference)
//
#include <hip/hip_runtime.h>
#include <math.h>

#define N_VOX (96*96*96)        // 884736 voxels per volume
#define NVOL 8                  // 4 pred + 4 target volumes
#define NEL (4*N_VOX)           // 3538944 elements in pred/target
#define PLANE (96*96)           // 9216

// tile geometry for local CCL: full d-span x TW x TH
#define TW 8
#define TH 8
#define TILES_W 12
#define TILES_H 12
#define TILE_VOX (96*TW*TH)     // 6144
#define TILE_WORDS (TILE_VOX/32) // 192

#define NBPLANES 11             // interior tile boundaries per axis
#define NPAIRS (2*NBPLANES)     // 22 boundary plane-pairs per volume
#define FACES_PER_VOL (2*NPAIRS*PLANE) // 405504 ushorts (w+h, 2 sides each)
#define BOUND_VOX (NPAIRS*PLANE)       // 202752 boundary edges per volume
#define MAXR 40192              // dense roots that fit in 157 KB LDS
#define FALLR 65536             // global fallback capacity (ushort ID space)
#define PAIRCAP 204800          // > BOUND_VOX -> unique-pair list can't overflow
#define HT2N 4096               // per-plane dedup hash entries (16 KB LDS)
#define MAX_PROBES 16

// ---------------------------------------------------------------------------
// generic-pointer union-find (works on LDS or global array). Labels only
// decrease (atomicMin) -> monotone, no cycles.
__device__ __forceinline__ int uf_find(int* __restrict__ L, int x) {
    int r = x;
    int p = L[r];
    while (p != r) { r = p; p = L[r]; }
    if (r != x) atomicMin(&L[x], r);     // path compression (monotone-safe)
    return r;
}

// returns # destroyed self-loops (exact union events).
__device__ __forceinline__ int uf_merge(int* __restrict__ L, int l1, int l2) {
    int ev = 0;
    while (l1 != l2) {
        if (l1 < l2) { int t = l1; l1 = l2; l2 = t; }   // l1 > l2
        int l3 = atomicMin(&L[l1], l2);
        if (l3 == l1) { ev++; l1 = l2; }
        else l1 = l3;
    }
    return ev;
}

// merge on LDS tile labels (links only run-start slots)
__device__ __forceinline__ void merge_local(int* lab, int l1, int l2) {
    while (l1 != l2 && l1 != lab[l1]) l1 = lab[l1];
    while (l1 != l2 && l2 != lab[l2]) l2 = lab[l2];
    while (l1 != l2) {
        if (l1 < l2) { int t = l1; l1 = l2; l2 = t; }
        int l3 = atomicMin(&lab[l1], l2);
        l1 = (l3 == l1) ? l2 : l3;
    }
}

// start index of the consecutive-fg d-run containing fg voxel i (d = i%96).
__device__ __forceinline__ int run_start(const unsigned* fm, int i, int d) {
    int rowb = (i - d) >> 5;
    int k = d >> 5, bit = d & 31;
    unsigned below = bit ? (~fm[rowb + k] & ((1u << bit) - 1)) : 0u;
    int z = -1;
    if (below) z = (k << 5) + 31 - __builtin_clz(below);
    else if (k > 0) {
        unsigned n1 = ~fm[rowb + k - 1];
        if (n1) z = ((k - 1) << 5) + 31 - __builtin_clz(n1);
        else if (k > 1) {
            unsigned n0 = ~fm[rowb];
            if (n0) z = 31 - __builtin_clz(n0);
        }
    }
    return (i - d) + z + 1;
}

// ---------------------------------------------------------------------------
// Phase 1: run-based per-tile CCL in LDS. Roots get DENSE per-volume IDs
// (block base via one atomicAdd on rootcnt[v] + intra-block wave scan).
// Outputs ONLY:
//   (a) compact ushort face arrays (dense root IDs, 0xFFFF = bg) for the
//       4 interior-adjacent tile faces, ushort4-coalesced;
//   (b) rootcnt[v] += #tile roots; acc += focal partial (pred volumes).
// No global label volume, no scattered root-slot writes.
__global__ __launch_bounds__(256) void ccl_local(const float* __restrict__ pred,
                                                 const float* __restrict__ targ,
                                                 unsigned short* __restrict__ faces,
                                                 int* __restrict__ rootcnt,
                                                 float* __restrict__ acc,
                                                 int vbase) {
    __shared__ int lab[TILE_VOX];            // 24 KB
    __shared__ unsigned fm[TILE_WORDS];      // 768 B fg bit array
    __shared__ float fws[4];
    __shared__ int   iws[4];
    __shared__ int   gbase;

    int vloc = blockIdx.y;
    int v = vbase + vloc;
    int tile = blockIdx.x;                   // 0..143
    int tw = tile % TILES_W, th = tile / TILES_W;
    int w0 = tw * TW, h0 = th * TH;
    int tbase = h0 * PLANE + w0 * 96;        // global index of tile origin
    unsigned short* Fw = faces + (size_t)vloc * FACES_PER_VOL;  // [b][side][h*96+d]
    unsigned short* Fh = Fw + 2 * NBPLANES * PLANE;             // [b][side][w*96+d]

    // ---- load: fg bits via ballot; fast focal partial for pred volumes ----
    float fsum = 0.0f;
    for (int it = 0; it < TILE_VOX / 256; it++) {
        int i = it * 256 + threadIdx.x;
        int lh = i / 768;                    // i = lh*768 + lw*96 + d
        int j = tbase + i + lh * 8448;       // global voxel index
        bool f;
        if (v < 4) {
            float xv = pred[(size_t)v * N_VOX + j];
            float tv = targ[(size_t)v * N_VOX + j];
            f = xv > 0.0f;                   // sigmoid(x)>0.5 <=> x>0
            float m   = (tv == 1.0f) ? -xv : xv;
            float at  = (tv == 1.0f) ? 0.25f : 0.75f;
            float e   = __expf(-fabsf(m));
            float inv = 1.0f / (1.0f + e);
            float sig = inv * ((m >= 0.0f) ? 1.0f : e);    // sigmoid(m)
            float sp  = fmaxf(m, 0.0f) + __logf(1.0f + e); // softplus(m)
            fsum += at * sig * sig * sp;
        } else {
            f = targ[(size_t)(v - 4) * N_VOX + j] > 0.5f;
        }
        unsigned long long bal = __ballot(f);
        if ((threadIdx.x & 63) == 0) {
            fm[i >> 5]       = (unsigned)bal;
            fm[(i >> 5) + 1] = (unsigned)(bal >> 32);
        }
        lab[i] = i;
    }
    __syncthreads();

    // ---- merge: word-level overlap-segment starts, w then h direction ----
    for (int t = threadIdx.x; t < 336; t += 256) {
        bool wdir = t < 168;
        int tt = wdir ? t : t - 168;
        int lh, lw, k;
        if (wdir) { lh = tt / 21; int rem = tt % 21; lw = rem / 3; k = rem % 3; }
        else      { lh = tt / 24; int rem = tt % 24; lw = rem / 3; k = rem % 3; }
        int wb = (lh * 8 + lw) * 3 + k;
        int nb = wb + (wdir ? 3 : 24);
        unsigned ov = fm[wb] & fm[nb];
        if (!ov) continue;
        unsigned carry = (k > 0) ? ((fm[wb - 1] & fm[nb - 1]) >> 31) : 0u;
        unsigned starts = ov & ~((ov << 1) | carry);
        int base_i = wb << 5;
        int dir = wdir ? 96 : 768;
        while (starts) {
            int b = __builtin_ctz(starts);
            starts &= starts - 1;
            int i = base_i + b;
            int d = (k << 5) + b;
            merge_local(lab, run_start(fm, i, d), run_start(fm, i + dir, d));
        }
    }
    __syncthreads();

    // ---- R1: count tile roots (start slots with lab[i]==i) per thread ----
    int myroots = 0;
    for (int t = threadIdx.x; t < TILE_WORDS; t += 256) {
        unsigned m = fm[t];
        if (!m) continue;
        unsigned carry = (t % 3) ? (fm[t - 1] >> 31) : 0u;
        unsigned starts = m & ~((m << 1) | carry);
        int base_i = t << 5;
        while (starts) {
            int b = __builtin_ctz(starts); starts &= starts - 1;
            if (lab[base_i + b] == base_i + b) myroots++;
        }
    }
    // wave inclusive scan + cross-wave prefix + one atomicAdd for the base
    int s = myroots;
    for (int off = 1; off < 64; off <<= 1) {
        int tv2 = __shfl_up(s, off, 64);
        if ((threadIdx.x & 63) >= off) s += tv2;
    }
    int wid = threadIdx.x >> 6;
    if ((threadIdx.x & 63) == 63) iws[wid] = s;
    __syncthreads();
    int wbase = 0;
    for (int k = 0; k < wid; k++) wbase += iws[k];
    if (threadIdx.x == 0)
        gbase = atomicAdd(&rootcnt[v], iws[0] + iws[1] + iws[2] + iws[3]);
    __syncthreads();
    int nid = gbase + wbase + (s - myroots);   // exclusive base for my roots

    // ---- R2: assign dense IDs to roots (each thread owns its words) ----
    for (int t = threadIdx.x; t < TILE_WORDS; t += 256) {
        unsigned m = fm[t];
        if (!m) continue;
        unsigned carry = (t % 3) ? (fm[t - 1] >> 31) : 0u;
        unsigned starts = m & ~((m << 1) | carry);
        int base_i = t << 5;
        while (starts) {
            int b = __builtin_ctz(starts); starts &= starts - 1;
            int i = base_i + b;
            if (lab[i] == i) lab[i] = ~(nid++);
        }
    }
    __syncthreads();

    // ---- R3: flatten non-root starts to ~denseID (chains end negative) ----
    for (int t = threadIdx.x; t < TILE_WORDS; t += 256) {
        unsigned m = fm[t];
        if (!m) continue;
        unsigned carry = (t % 3) ? (fm[t - 1] >> 31) : 0u;
        unsigned starts = m & ~((m << 1) | carry);
        int base_i = t << 5;
        while (starts) {
            int b = __builtin_ctz(starts); starts &= starts - 1;
            int i = base_i + b;
            int p = lab[i];
            if (p >= 0) {                    // non-root start
                int r = p, q2 = lab[r];
                while (q2 >= 0) { r = q2; q2 = lab[r]; }
                lab[i] = q2;                 // adopt finalized ~denseID
            }
        }
    }
    __syncthreads();

    // ---- resolve + store the 4 interior-adjacent faces (ushort4 groups) ----
    for (int t = threadIdx.x; t < 768; t += 256) {
        int f  = t / 192;
        int g  = t % 192;
        int u  = g / 24;                     // row within face (lh or lw)
        int d4 = (g % 24) * 4;
        int i0; unsigned short* dst;
        if (f == 0) {
            if (tw == 0) continue;
            i0  = u * 768 + d4;
            dst = Fw + ((tw - 1) * 2 + 1) * PLANE + (h0 + u) * 96 + d4;
        } else if (f == 1) {
            if (tw == TILES_W - 1) continue;
            i0  = u * 768 + 7 * 96 + d4;
            dst = Fw + (tw * 2) * PLANE + (h0 + u) * 96 + d4;
        } else if (f == 2) {
            if (th == 0) continue;
            i0  = u * 96 + d4;
            dst = Fh + ((th - 1) * 2 + 1) * PLANE + (w0 + u) * 96 + d4;
        } else {
            if (th == TILES_H - 1) continue;
            i0  = 7 * 768 + u * 96 + d4;
            dst = Fh + (th * 2) * PLANE + (w0 + u) * 96 + d4;
        }
        unsigned mw = fm[i0 >> 5];           // bits d4..d4+3 in one word
        unsigned short vals[4];
        bool prevf = false;
        for (int q = 0; q < 4; q++) {
            bool fb = (mw >> ((d4 & 31) + q)) & 1;
            if (fb) vals[q] = prevf ? vals[q - 1]
                                    : (unsigned short)(~lab[run_start(fm, i0 + q, d4 + q)]);
            else vals[q] = 0xFFFFu;
            prevf = fb;
        }
        *(ushort4*)dst = make_ushort4(vals[0], vals[1], vals[2], vals[3]);
    }

    // ---- wave-shuffle reduction: focal partial ----
    for (int off = 32; off; off >>= 1) fsum += __shfl_down(fsum, off, 64);
    if ((threadIdx.x & 63) == 0) fws[wid] = fsum;
    __syncthreads();
    if (threadIdx.x == 0) {
        float ft = fws[0] + fws[1] + fws[2] + fws[3];
        if (v < 4 && ft != 0.0f) atomicAdd(acc, ft);
    }
}

// ---------------------------------------------------------------------------
// Phase 2a: WIDE pair extraction + dedup. One block per (plane-pair, volume)
// = 22 x nv blocks. Each block streams its 2x9216-ushort plane coalesced,
// extracts overlap-segment-start (a,b) pairs, dedups them through a private
// 16 KB LDS hash (~1700 raw -> ~300 unique), and appends uniques to the
// per-volume global pair list. Cross-plane dupes / probe-cap dupes are kept
// (harmless: they find equal roots downstream -> 0 events).
__global__ __launch_bounds__(256) void ccl_pairs(const unsigned short* __restrict__ faces,
                                                 unsigned* __restrict__ pairs,
                                                 int* __restrict__ pcount,
                                                 int vbase) {
    __shared__ unsigned ht[HT2N];            // 16 KB
    for (int i = threadIdx.x; i < HT2N; i += 256) ht[i] = 0xFFFFFFFFu;
    __syncthreads();

    int f    = blockIdx.x;                   // plane pair 0..21
    int vloc = blockIdx.y;
    int v    = vbase + vloc;
    const unsigned short* F = faces + (size_t)vloc * FACES_PER_VOL;
    const unsigned short* A = F + (size_t)(2 * f) * PLANE;
    const unsigned short* B = A + PLANE;
    unsigned* pb = pairs + (size_t)vloc * PAIRCAP;

    const int GPP = PLANE / 8;               // 1152 8-wide groups
    for (int g = threadIdx.x; g < GPP; g += 256) {
        int e8 = g * 8;
        int4 aw = *(const int4*)(A + e8);    // 8 ushorts, coalesced 16B
        int4 bw = *(const int4*)(B + e8);
        unsigned a32[4] = {(unsigned)aw.x, (unsigned)aw.y, (unsigned)aw.z, (unsigned)aw.w};
        unsigned b32[4] = {(unsigned)bw.x, (unsigned)bw.y, (unsigned)bw.z, (unsigned)bw.w};
        bool pf = false;
        if (e8 % 96) pf = (A[e8 - 1] != 0xFFFFu) && (B[e8 - 1] != 0xFFFFu);
        #pragma unroll
        for (int q = 0; q < 8; q++) {
            unsigned av = (a32[q >> 1] >> ((q & 1) * 16)) & 0xFFFFu;
            unsigned bv = (b32[q >> 1] >> ((q & 1) * 16)) & 0xFFFFu;
            bool f2 = (av != 0xFFFFu) && (bv != 0xFFFFu);
            if (f2 && !pf && av != bv) {     // overlap-segment start along d
                unsigned lo = av < bv ? av : bv;
                unsigned hi = av < bv ? bv : av;
                unsigned key = (lo << 16) | hi;
                unsigned h = (key * 2654435761u) >> 20;   // -> 12-bit slot
                bool fresh = false;
                for (int pr = 0; pr < MAX_PROBES; pr++) {
                    unsigned prev = atomicCAS(&ht[h], 0xFFFFFFFFu, key);
                    if (prev == 0xFFFFFFFFu) { fresh = true; break; }
                    if (prev == key) break;
                    h = (h + 1) & (HT2N - 1);
                    if (pr == MAX_PROBES - 1) fresh = true;  // cap: keep dupe
                }
                if (fresh) {
                    int ix = atomicAdd(&pcount[v], 1);
                    pb[ix] = key;            // ix < PAIRCAP by construction
                }
            }
            pf = f2;
        }
    }
}

// ---------------------------------------------------------------------------
// Phase 2b: NARROW exact union-find. One 1024-thread block per volume over
// the dense root ID space in 157 KB LDS; processes only the ~6.5k deduped
// pairs (~7/thread). components = roots - events (events counted exactly as
// destroyed self-loops).
__global__ __launch_bounds__(1024) void ccl_union(const unsigned* __restrict__ pairs,
                                                  int* __restrict__ gfall,
                                                  const int* __restrict__ rootcnt,
                                                  const int* __restrict__ pcount,
                                                  int* __restrict__ events,
                                                  int vbase) {
    __shared__ int slab[MAXR];               // 157 KB dense union-find
    __shared__ int wsum[16];
    int vloc = blockIdx.x;
    int v = vbase + vloc;
    int R  = rootcnt[v];
    int np = pcount[v];
    const unsigned* pb = pairs + (size_t)vloc * PAIRCAP;

    int* lab = (R <= MAXR) ? (int*)slab : (gfall + (size_t)vloc * FALLR);
    for (int i = threadIdx.x; i < R; i += 1024) lab[i] = i;
    __syncthreads();

    int ev = 0;
    for (int i = threadIdx.x; i < np; i += 1024) {
        unsigned key = pb[i];
        int a = (int)(key >> 16), b = (int)(key & 0xFFFFu);
        int ra = uf_find(lab, a);
        int rb = uf_find(lab, b);
        if (ra != rb) ev += uf_merge(lab, ra, rb);
    }

    // block reduction of union events
    for (int off = 32; off; off >>= 1) ev += __shfl_down(ev, off, 64);
    if ((threadIdx.x & 63) == 0) wsum[threadIdx.x >> 6] = ev;
    __syncthreads();
    if (threadIdx.x == 0) {
        int tot = 0;
        for (int k = 0; k < 16; k++) tot += wsum[k];
        events[v] = tot;                     // single writer per volume
    }
}

// ---------------------------------------------------------------------------
// components[v] = rootcnt[v] - events[v]
__global__ void finalize_kernel(const float* __restrict__ acc,
                                const int* __restrict__ rootcnt,
                                const int* __restrict__ events,
                                float* __restrict__ out) {
    float focal = acc[0] / (float)NEL;
    float c[NVOL];
    for (int v = 0; v < NVOL; v++) c[v] = (float)(rootcnt[v] - events[v]);
    float dp0 = 0.5f * (c[0] + c[2]);
    float dp1 = 0.5f * (c[1] + c[3]);
    float dt0 = 0.5f * (c[4] + c[6]);
    float dt1 = 0.5f * (c[5] + c[7]);
    float topo = 0.5f * (fabsf(dp0 - dt0) + fabsf(dp1 - dt1));
    out[0] = focal + 0.1f * topo;
}

// ---------------------------------------------------------------------------
extern "C" void kernel_launch(void* const* d_in, const int* in_sizes, int n_in,
                              void* d_out, int out_size, void* d_ws, size_t ws_size,
                              hipStream_t stream) {
    const float* pred = (const float*)d_in[0];
    const float* targ = (const float*)d_in[1];
    float* out = (float*)d_out;

    // ws header (256 B, zeroed): [0] float acc; [64] int rootcnt[8];
    // [128] int events[8]; [192] int pcount[8].
    // [256..) ushort faces[vp*FACES_PER_VOL] | uint pairs[vp*PAIRCAP]
    //         | int gfall[vp*FALLR]
    float* acc     = (float*)d_ws;
    int*   rootcnt = (int*)((char*)d_ws + 64);
    int*   events  = (int*)((char*)d_ws + 128);
    int*   pcount  = (int*)((char*)d_ws + 192);
    unsigned short* faces = (unsigned short*)((char*)d_ws + 256);

    size_t per_vol = (size_t)FACES_PER_VOL * 2 + (size_t)PAIRCAP * 4
                   + (size_t)FALLR * 4;
    size_t avail   = (ws_size > 256) ? ws_size - 256 : 0;
    int vols_per_pass = (int)(avail / per_vol);
    if (vols_per_pass > NVOL) vols_per_pass = NVOL;
    if (vols_per_pass < 1) vols_per_pass = 1;
    unsigned* pairs = (unsigned*)(faces + (size_t)vols_per_pass * FACES_PER_VOL);
    int* gfall = (int*)(pairs + (size_t)vols_per_pass * PAIRCAP);

    hipMemsetAsync(d_ws, 0, 256, stream);

    for (int vbase = 0; vbase < NVOL; vbase += vols_per_pass) {
        int nv = NVOL - vbase;
        if (nv > vols_per_pass) nv = vols_per_pass;
        dim3 tgrid(TILES_W * TILES_H, nv);
        ccl_local<<<tgrid, dim3(256), 0, stream>>>(pred, targ, faces,
                                                   rootcnt, acc, vbase);
        dim3 pgrid(NPAIRS, nv);
        ccl_pairs<<<pgrid, dim3(256), 0, stream>>>(faces, pairs, pcount, vbase);
        ccl_union<<<dim3(nv), dim3(1024), 0, stream>>>(pairs, gfall, rootcnt,
                                                       pcount, events, vbase);
    }

    finalize_kernel<<<1, 1, 0, stream>>>(acc, rootcnt, events, out);
}

// Round 5
// 169.044 us; speedup vs baseline: 2.3458x; 2.3458x over previous
//
#include <hip/hip_runtime.h>
#include <math.h>

#define N_VOX (96*96*96)        // 884736 voxels per volume
#define NVOL 8                  // 4 pred + 4 target volumes
#define NEL (4*N_VOX)           // 3538944 elements in pred/target
#define PLANE (96*96)           // 9216

// tile geometry for local CCL: full d-span x TW x TH
#define TW 8
#define TH 8
#define TILES_W 12
#define TILES_H 12
#define TILE_VOX (96*TW*TH)     // 6144
#define TILE_WORDS (TILE_VOX/32) // 192

#define NBPLANES 11             // interior tile boundaries per axis
#define NPAIRS (2*NBPLANES)     // 22 boundary plane-pairs per volume
#define FACES_PER_VOL (2*NPAIRS*PLANE) // 405504 ushorts (w+h, 2 sides each)
#define MAXR 40192              // dense roots that fit in 157 KB LDS
#define FALLR 65536             // global fallback capacity (ushort ID space)
#define SEGCAP 4608             // hard bound: <=48 starts/line * 96 lines/plane
#define HT2N 4096               // per-plane dedup hash entries (16 KB LDS)
#define MAX_PROBES 16

// workspace header layout (4 KB, zeroed once). Per-volume counters are
// strided to 128 B so 8 volumes never share a cache line (round-4 lesson:
// same-line cross-XCD atomics serialize at ~5 ns each).
#define WS_ACC   0
#define WS_ROOT  256            // int, volume v at int-index (v<<5)
#define WS_EVT   1536           // int, volume v at int-index (v<<5)
#define WS_PCNT  2816           // int [v*NPAIRS + f], single writer each
#define WS_HDR   4096

// ---------------------------------------------------------------------------
// generic-pointer union-find (works on LDS or global array). Labels only
// decrease (atomicMin) -> monotone, no cycles.
__device__ __forceinline__ int uf_find(int* __restrict__ L, int x) {
    int r = x;
    int p = L[r];
    while (p != r) { r = p; p = L[r]; }
    if (r != x) atomicMin(&L[x], r);     // path compression (monotone-safe)
    return r;
}

// returns # destroyed self-loops (exact union events).
__device__ __forceinline__ int uf_merge(int* __restrict__ L, int l1, int l2) {
    int ev = 0;
    while (l1 != l2) {
        if (l1 < l2) { int t = l1; l1 = l2; l2 = t; }   // l1 > l2
        int l3 = atomicMin(&L[l1], l2);
        if (l3 == l1) { ev++; l1 = l2; }
        else l1 = l3;
    }
    return ev;
}

// merge on LDS tile labels (links only run-start slots)
__device__ __forceinline__ void merge_local(int* lab, int l1, int l2) {
    while (l1 != l2 && l1 != lab[l1]) l1 = lab[l1];
    while (l1 != l2 && l2 != lab[l2]) l2 = lab[l2];
    while (l1 != l2) {
        if (l1 < l2) { int t = l1; l1 = l2; l2 = t; }
        int l3 = atomicMin(&lab[l1], l2);
        l1 = (l3 == l1) ? l2 : l3;
    }
}

// start index of the consecutive-fg d-run containing fg voxel i (d = i%96).
__device__ __forceinline__ int run_start(const unsigned* fm, int i, int d) {
    int rowb = (i - d) >> 5;
    int k = d >> 5, bit = d & 31;
    unsigned below = bit ? (~fm[rowb + k] & ((1u << bit) - 1)) : 0u;
    int z = -1;
    if (below) z = (k << 5) + 31 - __builtin_clz(below);
    else if (k > 0) {
        unsigned n1 = ~fm[rowb + k - 1];
        if (n1) z = ((k - 1) << 5) + 31 - __builtin_clz(n1);
        else if (k > 1) {
            unsigned n0 = ~fm[rowb];
            if (n0) z = 31 - __builtin_clz(n0);
        }
    }
    return (i - d) + z + 1;
}

// ---------------------------------------------------------------------------
// Phase 1: run-based per-tile CCL in LDS. Roots get DENSE per-volume IDs
// (block base via one atomicAdd on rootcnt[v] + intra-block wave scan).
// Outputs ONLY:
//   (a) compact ushort face arrays (dense root IDs, 0xFFFF = bg) for the
//       4 interior-adjacent tile faces, ushort4-coalesced;
//   (b) rootcnt[v] += #tile roots; acc += focal partial (pred volumes).
// No global label volume, no scattered root-slot writes.
__global__ __launch_bounds__(256) void ccl_local(const float* __restrict__ pred,
                                                 const float* __restrict__ targ,
                                                 unsigned short* __restrict__ faces,
                                                 int* __restrict__ rootcnt,
                                                 float* __restrict__ acc,
                                                 int vbase) {
    __shared__ int lab[TILE_VOX];            // 24 KB
    __shared__ unsigned fm[TILE_WORDS];      // 768 B fg bit array
    __shared__ float fws[4];
    __shared__ int   iws[4];
    __shared__ int   gbase;

    int vloc = blockIdx.y;
    int v = vbase + vloc;
    int tile = blockIdx.x;                   // 0..143
    int tw = tile % TILES_W, th = tile / TILES_W;
    int w0 = tw * TW, h0 = th * TH;
    int tbase = h0 * PLANE + w0 * 96;        // global index of tile origin
    unsigned short* Fw = faces + (size_t)vloc * FACES_PER_VOL;  // [b][side][h*96+d]
    unsigned short* Fh = Fw + 2 * NBPLANES * PLANE;             // [b][side][w*96+d]

    // ---- load: fg bits via ballot; fast focal partial for pred volumes ----
    float fsum = 0.0f;
    for (int it = 0; it < TILE_VOX / 256; it++) {
        int i = it * 256 + threadIdx.x;
        int lh = i / 768;                    // i = lh*768 + lw*96 + d
        int j = tbase + i + lh * 8448;       // global voxel index
        bool f;
        if (v < 4) {
            float xv = pred[(size_t)v * N_VOX + j];
            float tv = targ[(size_t)v * N_VOX + j];
            f = xv > 0.0f;                   // sigmoid(x)>0.5 <=> x>0
            float m   = (tv == 1.0f) ? -xv : xv;
            float at  = (tv == 1.0f) ? 0.25f : 0.75f;
            float e   = __expf(-fabsf(m));
            float inv = 1.0f / (1.0f + e);
            float sig = inv * ((m >= 0.0f) ? 1.0f : e);    // sigmoid(m)
            float sp  = fmaxf(m, 0.0f) + __logf(1.0f + e); // softplus(m)
            fsum += at * sig * sig * sp;
        } else {
            f = targ[(size_t)(v - 4) * N_VOX + j] > 0.5f;
        }
        unsigned long long bal = __ballot(f);
        if ((threadIdx.x & 63) == 0) {
            fm[i >> 5]       = (unsigned)bal;
            fm[(i >> 5) + 1] = (unsigned)(bal >> 32);
        }
        lab[i] = i;
    }
    __syncthreads();

    // ---- merge: word-level overlap-segment starts, w then h direction ----
    for (int t = threadIdx.x; t < 336; t += 256) {
        bool wdir = t < 168;
        int tt = wdir ? t : t - 168;
        int lh, lw, k;
        if (wdir) { lh = tt / 21; int rem = tt % 21; lw = rem / 3; k = rem % 3; }
        else      { lh = tt / 24; int rem = tt % 24; lw = rem / 3; k = rem % 3; }
        int wb = (lh * 8 + lw) * 3 + k;
        int nb = wb + (wdir ? 3 : 24);
        unsigned ov = fm[wb] & fm[nb];
        if (!ov) continue;
        unsigned carry = (k > 0) ? ((fm[wb - 1] & fm[nb - 1]) >> 31) : 0u;
        unsigned starts = ov & ~((ov << 1) | carry);
        int base_i = wb << 5;
        int dir = wdir ? 96 : 768;
        while (starts) {
            int b = __builtin_ctz(starts);
            starts &= starts - 1;
            int i = base_i + b;
            int d = (k << 5) + b;
            merge_local(lab, run_start(fm, i, d), run_start(fm, i + dir, d));
        }
    }
    __syncthreads();

    // ---- R1: count tile roots (start slots with lab[i]==i) per thread ----
    int myroots = 0;
    for (int t = threadIdx.x; t < TILE_WORDS; t += 256) {
        unsigned m = fm[t];
        if (!m) continue;
        unsigned carry = (t % 3) ? (fm[t - 1] >> 31) : 0u;
        unsigned starts = m & ~((m << 1) | carry);
        int base_i = t << 5;
        while (starts) {
            int b = __builtin_ctz(starts); starts &= starts - 1;
            if (lab[base_i + b] == base_i + b) myroots++;
        }
    }
    // wave inclusive scan + cross-wave prefix + one atomicAdd for the base
    int s = myroots;
    for (int off = 1; off < 64; off <<= 1) {
        int tv2 = __shfl_up(s, off, 64);
        if ((threadIdx.x & 63) >= off) s += tv2;
    }
    int wid = threadIdx.x >> 6;
    if ((threadIdx.x & 63) == 63) iws[wid] = s;
    __syncthreads();
    int wbase = 0;
    for (int k = 0; k < wid; k++) wbase += iws[k];
    if (threadIdx.x == 0)
        gbase = atomicAdd(&rootcnt[v << 5], iws[0] + iws[1] + iws[2] + iws[3]);
    __syncthreads();
    int nid = gbase + wbase + (s - myroots);   // exclusive base for my roots

    // ---- R2: assign dense IDs to roots (each thread owns its words) ----
    for (int t = threadIdx.x; t < TILE_WORDS; t += 256) {
        unsigned m = fm[t];
        if (!m) continue;
        unsigned carry = (t % 3) ? (fm[t - 1] >> 31) : 0u;
        unsigned starts = m & ~((m << 1) | carry);
        int base_i = t << 5;
        while (starts) {
            int b = __builtin_ctz(starts); starts &= starts - 1;
            int i = base_i + b;
            if (lab[i] == i) lab[i] = ~(nid++);
        }
    }
    __syncthreads();

    // ---- R3: flatten non-root starts to ~denseID (chains end negative) ----
    for (int t = threadIdx.x; t < TILE_WORDS; t += 256) {
        unsigned m = fm[t];
        if (!m) continue;
        unsigned carry = (t % 3) ? (fm[t - 1] >> 31) : 0u;
        unsigned starts = m & ~((m << 1) | carry);
        int base_i = t << 5;
        while (starts) {
            int b = __builtin_ctz(starts); starts &= starts - 1;
            int i = base_i + b;
            int p = lab[i];
            if (p >= 0) {                    // non-root start
                int r = p, q2 = lab[r];
                while (q2 >= 0) { r = q2; q2 = lab[r]; }
                lab[i] = q2;                 // adopt finalized ~denseID
            }
        }
    }
    __syncthreads();

    // ---- resolve + store the 4 interior-adjacent faces (ushort4 groups) ----
    for (int t = threadIdx.x; t < 768; t += 256) {
        int f  = t / 192;
        int g  = t % 192;
        int u  = g / 24;                     // row within face (lh or lw)
        int d4 = (g % 24) * 4;
        int i0; unsigned short* dst;
        if (f == 0) {
            if (tw == 0) continue;
            i0  = u * 768 + d4;
            dst = Fw + ((tw - 1) * 2 + 1) * PLANE + (h0 + u) * 96 + d4;
        } else if (f == 1) {
            if (tw == TILES_W - 1) continue;
            i0  = u * 768 + 7 * 96 + d4;
            dst = Fw + (tw * 2) * PLANE + (h0 + u) * 96 + d4;
        } else if (f == 2) {
            if (th == 0) continue;
            i0  = u * 96 + d4;
            dst = Fh + ((th - 1) * 2 + 1) * PLANE + (w0 + u) * 96 + d4;
        } else {
            if (th == TILES_H - 1) continue;
            i0  = 7 * 768 + u * 96 + d4;
            dst = Fh + (th * 2) * PLANE + (w0 + u) * 96 + d4;
        }
        unsigned mw = fm[i0 >> 5];           // bits d4..d4+3 in one word
        unsigned short vals[4];
        bool prevf = false;
        for (int q = 0; q < 4; q++) {
            bool fb = (mw >> ((d4 & 31) + q)) & 1;
            if (fb) vals[q] = prevf ? vals[q - 1]
                                    : (unsigned short)(~lab[run_start(fm, i0 + q, d4 + q)]);
            else vals[q] = 0xFFFFu;
            prevf = fb;
        }
        *(ushort4*)dst = make_ushort4(vals[0], vals[1], vals[2], vals[3]);
    }

    // ---- wave-shuffle reduction: focal partial ----
    for (int off = 32; off; off >>= 1) fsum += __shfl_down(fsum, off, 64);
    if ((threadIdx.x & 63) == 0) fws[wid] = fsum;
    __syncthreads();
    if (threadIdx.x == 0) {
        float ft = fws[0] + fws[1] + fws[2] + fws[3];
        if (v < 4 && ft != 0.0f) atomicAdd(acc, ft);
    }
}

// ---------------------------------------------------------------------------
// Phase 2a: WIDE pair extraction + dedup. One block per (plane-pair, volume).
// Each block streams its 2x9216-ushort plane coalesced, extracts overlap-
// segment-start (a,b) pairs, dedups via a private 16 KB LDS hash, and writes
// uniques to its PRIVATE global segment indexed by an LDS counter -- zero
// global atomics (round-4 fix: the shared pcount line serialized ~53k
// cross-XCD RMWs at ~5ns each = 258us). Per-plane dedup == global dedup:
// a tile-pair's face lies in exactly one plane. Probe-cap dupes kept
// (harmless: equal roots downstream -> 0 events). uniques <= 4608 = SEGCAP.
__global__ __launch_bounds__(256) void ccl_pairs(const unsigned short* __restrict__ faces,
                                                 unsigned* __restrict__ pairs,
                                                 int* __restrict__ pcnt,
                                                 int vbase) {
    __shared__ unsigned ht[HT2N];            // 16 KB
    __shared__ int nloc;
    for (int i = threadIdx.x; i < HT2N; i += 256) ht[i] = 0xFFFFFFFFu;
    if (threadIdx.x == 0) nloc = 0;
    __syncthreads();

    int f    = blockIdx.x;                   // plane pair 0..21
    int vloc = blockIdx.y;
    int v    = vbase + vloc;
    const unsigned short* A = faces + (size_t)vloc * FACES_PER_VOL
                                    + (size_t)(2 * f) * PLANE;
    const unsigned short* B = A + PLANE;
    unsigned* pb = pairs + ((size_t)vloc * NPAIRS + f) * SEGCAP;

    const int GPP = PLANE / 8;               // 1152 8-wide groups
    for (int g = threadIdx.x; g < GPP; g += 256) {
        int e8 = g * 8;
        int4 aw = *(const int4*)(A + e8);    // 8 ushorts, coalesced 16B
        int4 bw = *(const int4*)(B + e8);
        unsigned a32[4] = {(unsigned)aw.x, (unsigned)aw.y, (unsigned)aw.z, (unsigned)aw.w};
        unsigned b32[4] = {(unsigned)bw.x, (unsigned)bw.y, (unsigned)bw.z, (unsigned)bw.w};
        bool pf = false;
        if (e8 % 96) pf = (A[e8 - 1] != 0xFFFFu) && (B[e8 - 1] != 0xFFFFu);
        #pragma unroll
        for (int q = 0; q < 8; q++) {
            unsigned av = (a32[q >> 1] >> ((q & 1) * 16)) & 0xFFFFu;
            unsigned bv = (b32[q >> 1] >> ((q & 1) * 16)) & 0xFFFFu;
            bool f2 = (av != 0xFFFFu) && (bv != 0xFFFFu);
            if (f2 && !pf && av != bv) {     // overlap-segment start along d
                unsigned lo = av < bv ? av : bv;
                unsigned hi = av < bv ? bv : av;
                unsigned key = (lo << 16) | hi;
                unsigned h = (key * 2654435761u) >> 20;   // -> 12-bit slot
                bool fresh = false;
                for (int pr = 0; pr < MAX_PROBES; pr++) {
                    unsigned prev = atomicCAS(&ht[h], 0xFFFFFFFFu, key);
                    if (prev == 0xFFFFFFFFu) { fresh = true; break; }
                    if (prev == key) break;
                    h = (h + 1) & (HT2N - 1);
                    if (pr == MAX_PROBES - 1) fresh = true;  // cap: keep dupe
                }
                if (fresh) {
                    int ix = atomicAdd(&nloc, 1);    // LDS atomic, on-CU
                    pb[ix] = key;                    // ix < SEGCAP bound
                }
            }
            pf = f2;
        }
    }
    __syncthreads();
    if (threadIdx.x == 0) pcnt[v * NPAIRS + f] = nloc;   // single writer
}

// ---------------------------------------------------------------------------
// Phase 2b: NARROW exact union-find. One 1024-thread block per volume over
// the dense root ID space in 157 KB LDS; walks the 22 per-plane unique-pair
// segments (~6.5k pairs total, ~7/thread). components = roots - events
// (events counted exactly as destroyed self-loops).
__global__ __launch_bounds__(1024) void ccl_union(const unsigned* __restrict__ pairs,
                                                  int* __restrict__ gfall,
                                                  const int* __restrict__ rootcnt,
                                                  const int* __restrict__ pcnt,
                                                  int* __restrict__ events,
                                                  int vbase) {
    __shared__ int slab[MAXR];               // 157 KB dense union-find
    __shared__ int wsum[16];
    int vloc = blockIdx.x;
    int v = vbase + vloc;
    int R  = rootcnt[v << 5];

    int* lab = (R <= MAXR) ? (int*)slab : (gfall + (size_t)vloc * FALLR);
    for (int i = threadIdx.x; i < R; i += 1024) lab[i] = i;
    __syncthreads();

    int ev = 0;
    for (int f = 0; f < NPAIRS; f++) {
        int np = pcnt[v * NPAIRS + f];
        const unsigned* pb = pairs + ((size_t)vloc * NPAIRS + f) * SEGCAP;
        for (int i = threadIdx.x; i < np; i += 1024) {
            unsigned key = pb[i];
            int a = (int)(key >> 16), b = (int)(key & 0xFFFFu);
            int ra = uf_find(lab, a);
            int rb = uf_find(lab, b);
            if (ra != rb) ev += uf_merge(lab, ra, rb);
        }
    }

    // block reduction of union events
    for (int off = 32; off; off >>= 1) ev += __shfl_down(ev, off, 64);
    if ((threadIdx.x & 63) == 0) wsum[threadIdx.x >> 6] = ev;
    __syncthreads();
    if (threadIdx.x == 0) {
        int tot = 0;
        for (int k = 0; k < 16; k++) tot += wsum[k];
        events[v << 5] = tot;                // single writer per volume
    }
}

// ---------------------------------------------------------------------------
// components[v] = rootcnt[v] - events[v]
__global__ void finalize_kernel(const float* __restrict__ acc,
                                const int* __restrict__ rootcnt,
                                const int* __restrict__ events,
                                float* __restrict__ out) {
    float focal = acc[0] / (float)NEL;
    float c[NVOL];
    for (int v = 0; v < NVOL; v++)
        c[v] = (float)(rootcnt[v << 5] - events[v << 5]);
    float dp0 = 0.5f * (c[0] + c[2]);
    float dp1 = 0.5f * (c[1] + c[3]);
    float dt0 = 0.5f * (c[4] + c[6]);
    float dt1 = 0.5f * (c[5] + c[7]);
    float topo = 0.5f * (fabsf(dp0 - dt0) + fabsf(dp1 - dt1));
    out[0] = focal + 0.1f * topo;
}

// ---------------------------------------------------------------------------
extern "C" void kernel_launch(void* const* d_in, const int* in_sizes, int n_in,
                              void* d_out, int out_size, void* d_ws, size_t ws_size,
                              hipStream_t stream) {
    const float* pred = (const float*)d_in[0];
    const float* targ = (const float*)d_in[1];
    float* out = (float*)d_out;

    // header (4 KB, zeroed; per-volume counters strided to 128 B)
    float* acc     = (float*)((char*)d_ws + WS_ACC);
    int*   rootcnt = (int*)((char*)d_ws + WS_ROOT);
    int*   events  = (int*)((char*)d_ws + WS_EVT);
    int*   pcnt    = (int*)((char*)d_ws + WS_PCNT);
    unsigned short* faces = (unsigned short*)((char*)d_ws + WS_HDR);

    size_t per_vol = (size_t)FACES_PER_VOL * 2
                   + (size_t)NPAIRS * SEGCAP * 4
                   + (size_t)FALLR * 4;
    size_t avail   = (ws_size > WS_HDR) ? ws_size - WS_HDR : 0;
    int vols_per_pass = (int)(avail / per_vol);
    if (vols_per_pass > NVOL) vols_per_pass = NVOL;
    if (vols_per_pass < 1) vols_per_pass = 1;
    unsigned* pairs = (unsigned*)(faces + (size_t)vols_per_pass * FACES_PER_VOL);
    int* gfall = (int*)(pairs + (size_t)vols_per_pass * NPAIRS * SEGCAP);

    hipMemsetAsync(d_ws, 0, WS_HDR, stream);

    for (int vbase = 0; vbase < NVOL; vbase += vols_per_pass) {
        int nv = NVOL - vbase;
        if (nv > vols_per_pass) nv = vols_per_pass;
        dim3 tgrid(TILES_W * TILES_H, nv);
        ccl_local<<<tgrid, dim3(256), 0, stream>>>(pred, targ, faces,
                                                   rootcnt, acc, vbase);
        dim3 pgrid(NPAIRS, nv);
        ccl_pairs<<<pgrid, dim3(256), 0, stream>>>(faces, pairs, pcnt, vbase);
        ccl_union<<<dim3(nv), dim3(1024), 0, stream>>>(pairs, gfall, rootcnt,
                                                       pcnt, events, vbase);
    }

    finalize_kernel<<<1, 1, 0, stream>>>(acc, rootcnt, events, out);
}